// Round 6
// baseline (1546.866 us; speedup 1.0000x reference)
//
#include <hip/hip_runtime.h>

#define K_DIM 256
__device__ __forceinline__ float lrelu_f(float x) { return x >= 0.f ? x : 0.2f * x; }

// ---------------- graph prep kernels ----------------

__global__ __launch_bounds__(256) void hist_kernel(const int* __restrict__ dst,
                                                   int* __restrict__ cnt, int E) {
  int e = blockIdx.x * 256 + threadIdx.x;
  if (e < E) atomicAdd(&cnt[dst[e]], 1);
}

__global__ __launch_bounds__(256) void dinv_kernel(const int* __restrict__ cnt,
                                                   float* __restrict__ dinv, int n) {
  int i = blockIdx.x * 256 + threadIdx.x;
  if (i < n) dinv[i] = rsqrtf((float)cnt[i] + 1.0f);
}

__global__ __launch_bounds__(256) void scan1_kernel(const int* __restrict__ cnt,
                                                    int* __restrict__ incl,
                                                    int* __restrict__ bsum, int n) {
  __shared__ int sm[256];
  int t = threadIdx.x;
  int i = blockIdx.x * 256 + t;
  int v = (i < n) ? cnt[i] : 0;
  sm[t] = v;
  __syncthreads();
  for (int off = 1; off < 256; off <<= 1) {
    int u = (t >= off) ? sm[t - off] : 0;
    __syncthreads();
    sm[t] += u;
    __syncthreads();
  }
  if (i < n) incl[i] = sm[t];
  if (t == 255) bsum[blockIdx.x] = sm[255];
}

__global__ __launch_bounds__(256) void scan2_kernel(const int* __restrict__ bsum,
                                                    int* __restrict__ boff, int nb) {
  __shared__ int sm[256];
  int t = threadIdx.x;
  int v = (t < nb) ? bsum[t] : 0;
  sm[t] = v;
  __syncthreads();
  for (int off = 1; off < 256; off <<= 1) {
    int u = (t >= off) ? sm[t - off] : 0;
    __syncthreads();
    sm[t] += u;
    __syncthreads();
  }
  boff[t] = sm[t] - v;  // exclusive
}

__global__ __launch_bounds__(256) void scan3_kernel(const int* __restrict__ incl,
                                                    const int* __restrict__ boff,
                                                    int* __restrict__ rowptr, int n) {
  int i = blockIdx.x * 256 + threadIdx.x;
  if (i < n) rowptr[i + 1] = incl[i] + boff[blockIdx.x];
  if (i == 0) rowptr[0] = 0;
}

__global__ __launch_bounds__(256) void scatter_kernel(const int* __restrict__ src,
                                                      const int* __restrict__ dst,
                                                      const int* __restrict__ rowptr,
                                                      int* __restrict__ cursor,
                                                      const float* __restrict__ dinv,
                                                      int* __restrict__ esrc,
                                                      float* __restrict__ ew, int E) {
  int e = blockIdx.x * 256 + threadIdx.x;
  if (e < E) {
    int d = dst[e];
    int p = rowptr[d] + atomicAdd(&cursor[d], 1);
    int s = src[e];
    esrc[p] = s;
    ew[p] = dinv[s];
  }
}

// ---------------- GEMM: H[M,NCOLS] = act(A[M,256]) @ W[NCOLS,256]^T ----------------
// 128x128 tile, 256 threads, 8x8 microtile. BK=16, DOUBLE-BUFFERED LDS:
// one barrier per K-step; next slab's global loads issued before the FMA block
// so ~900cy mem latency hides under 2048cy of FMAs. LDS = 32 KB -> 5 blocks/CU cap.

template <bool LRELU, int NCOLS>
__global__ __launch_bounds__(256) void gemm_kernel(const float* __restrict__ A,
                                                   const float* __restrict__ W,
                                                   float* __restrict__ H, int M) {
  constexpr int BK = 16;
  constexpr int NSTEP = K_DIM / BK;
  __shared__ float As[2][BK][128];
  __shared__ float Ws[2][BK][128];
  const int bm = blockIdx.x * 128;
  const int bn = blockIdx.y * 128;
  const int tid = threadIdx.x;
  const int tx = tid & 15;   // N dir
  const int ty = tid >> 4;   // M dir
  const int lr = tid >> 2;   // staging row 0..63
  const int lk = (tid & 3) << 2;  // staging k quad

  int ra0 = bm + lr;      if (ra0 >= M) ra0 = M - 1;
  int ra1 = bm + 64 + lr; if (ra1 >= M) ra1 = M - 1;
  const float* Ag0 = A + (size_t)ra0 * K_DIM + lk;
  const float* Ag1 = A + (size_t)ra1 * K_DIM + lk;
  const float* Wg0 = W + (size_t)(bn + lr) * K_DIM + lk;
  const float* Wg1 = W + (size_t)(bn + 64 + lr) * K_DIM + lk;

  float4 pa0 = *(const float4*)(Ag0);
  float4 pa1 = *(const float4*)(Ag1);
  float4 pw0 = *(const float4*)(Wg0);
  float4 pw1 = *(const float4*)(Wg1);

  float acc[2][2][4][4];
#pragma unroll
  for (int a = 0; a < 2; a++)
#pragma unroll
    for (int b = 0; b < 2; b++)
#pragma unroll
      for (int i = 0; i < 4; i++)
#pragma unroll
        for (int j = 0; j < 4; j++) acc[a][b][i][j] = 0.f;

  // stage slab 0 into buffer 0
  {
    float4 a0 = pa0, a1 = pa1;
    if (LRELU) {
      a0.x = lrelu_f(a0.x); a0.y = lrelu_f(a0.y); a0.z = lrelu_f(a0.z); a0.w = lrelu_f(a0.w);
      a1.x = lrelu_f(a1.x); a1.y = lrelu_f(a1.y); a1.z = lrelu_f(a1.z); a1.w = lrelu_f(a1.w);
    }
    As[0][lk + 0][lr] = a0.x; As[0][lk + 1][lr] = a0.y;
    As[0][lk + 2][lr] = a0.z; As[0][lk + 3][lr] = a0.w;
    As[0][lk + 0][64 + lr] = a1.x; As[0][lk + 1][64 + lr] = a1.y;
    As[0][lk + 2][64 + lr] = a1.z; As[0][lk + 3][64 + lr] = a1.w;
    Ws[0][lk + 0][lr] = pw0.x; Ws[0][lk + 1][lr] = pw0.y;
    Ws[0][lk + 2][lr] = pw0.z; Ws[0][lk + 3][lr] = pw0.w;
    Ws[0][lk + 0][64 + lr] = pw1.x; Ws[0][lk + 1][64 + lr] = pw1.y;
    Ws[0][lk + 2][64 + lr] = pw1.z; Ws[0][lk + 3][64 + lr] = pw1.w;
  }

  for (int s = 0; s < NSTEP; ++s) {
    const int cur = s & 1;
    __syncthreads();
    if (s + 1 < NSTEP) {
      const int off = (s + 1) * BK;
      pa0 = *(const float4*)(Ag0 + off);
      pa1 = *(const float4*)(Ag1 + off);
      pw0 = *(const float4*)(Wg0 + off);
      pw1 = *(const float4*)(Wg1 + off);
    }
#pragma unroll
    for (int kk = 0; kk < BK; ++kk) {
      float4 va0 = *(const float4*)&As[cur][kk][ty * 4];
      float4 va1 = *(const float4*)&As[cur][kk][64 + ty * 4];
      float4 vb0 = *(const float4*)&Ws[cur][kk][tx * 4];
      float4 vb1 = *(const float4*)&Ws[cur][kk][64 + tx * 4];
      float a0[4] = {va0.x, va0.y, va0.z, va0.w};
      float a1[4] = {va1.x, va1.y, va1.z, va1.w};
      float b0[4] = {vb0.x, vb0.y, vb0.z, vb0.w};
      float b1[4] = {vb1.x, vb1.y, vb1.z, vb1.w};
#pragma unroll
      for (int i = 0; i < 4; i++)
#pragma unroll
        for (int j = 0; j < 4; j++) {
          acc[0][0][i][j] = fmaf(a0[i], b0[j], acc[0][0][i][j]);
          acc[0][1][i][j] = fmaf(a0[i], b1[j], acc[0][1][i][j]);
          acc[1][0][i][j] = fmaf(a1[i], b0[j], acc[1][0][i][j]);
          acc[1][1][i][j] = fmaf(a1[i], b1[j], acc[1][1][i][j]);
        }
    }
    if (s + 1 < NSTEP) {
      const int nxt = cur ^ 1;
      float4 a0 = pa0, a1 = pa1;
      if (LRELU) {
        a0.x = lrelu_f(a0.x); a0.y = lrelu_f(a0.y); a0.z = lrelu_f(a0.z); a0.w = lrelu_f(a0.w);
        a1.x = lrelu_f(a1.x); a1.y = lrelu_f(a1.y); a1.z = lrelu_f(a1.z); a1.w = lrelu_f(a1.w);
      }
      As[nxt][lk + 0][lr] = a0.x; As[nxt][lk + 1][lr] = a0.y;
      As[nxt][lk + 2][lr] = a0.z; As[nxt][lk + 3][lr] = a0.w;
      As[nxt][lk + 0][64 + lr] = a1.x; As[nxt][lk + 1][64 + lr] = a1.y;
      As[nxt][lk + 2][64 + lr] = a1.z; As[nxt][lk + 3][64 + lr] = a1.w;
      Ws[nxt][lk + 0][lr] = pw0.x; Ws[nxt][lk + 1][lr] = pw0.y;
      Ws[nxt][lk + 2][lr] = pw0.z; Ws[nxt][lk + 3][lr] = pw0.w;
      Ws[nxt][lk + 0][64 + lr] = pw1.x; Ws[nxt][lk + 1][64 + lr] = pw1.y;
      Ws[nxt][lk + 2][64 + lr] = pw1.z; Ws[nxt][lk + 3][64 + lr] = pw1.w;
    }
  }

#pragma unroll
  for (int mh = 0; mh < 2; ++mh)
#pragma unroll
    for (int i = 0; i < 4; i++) {
      int row = bm + mh * 64 + ty * 4 + i;
      if (row < M) {
#pragma unroll
        for (int nh = 0; nh < 2; ++nh) {
          float4 o;
          o.x = acc[mh][nh][i][0];
          o.y = acc[mh][nh][i][1];
          o.z = acc[mh][nh][i][2];
          o.w = acc[mh][nh][i][3];
          *(float4*)(H + (size_t)row * NCOLS + bn + nh * 64 + tx * 4) = o;
        }
      }
    }
}

// ---------------- aggregation: out[i] = dinv_i*(sum dinv_s*h_s) + dinv_i^2*h_i + b ----------------
// one wave per node; 64 lanes cover COLS floats. 4-way edge batching.
// NOTE (R5): do NOT couple this to an LDS-heavy consumer — gather needs high
// occupancy (71%) to sustain 3.7 TB/s; fused version at 19% occ ran at 1.8 TB/s.

template <int COLS>
__global__ __launch_bounds__(256) void aggregate_kernel(
    const float* __restrict__ H, const int* __restrict__ rowptr,
    const int* __restrict__ esrc, const float* __restrict__ ew,
    const float* __restrict__ dinv, const float* __restrict__ bias,
    float* __restrict__ out, int n) {
  const int lane = threadIdx.x & 63;
  const int node = blockIdx.x * 4 + (threadIdx.x >> 6);
  if (node >= n) return;
  constexpr int V = COLS / 64;
  const float di = dinv[node];
  float acc[V];
  if constexpr (V == 4) {
    float4 h = *(const float4*)(H + (size_t)node * COLS + lane * 4);
    acc[0] = di * h.x; acc[1] = di * h.y; acc[2] = di * h.z; acc[3] = di * h.w;
  } else {
    float2 h = *(const float2*)(H + (size_t)node * COLS + lane * 2);
    acc[0] = di * h.x; acc[1] = di * h.y;
  }
  const int e1 = rowptr[node + 1];
  int e = rowptr[node];
  for (; e + 4 <= e1; e += 4) {
    int s0 = esrc[e + 0], s1 = esrc[e + 1], s2 = esrc[e + 2], s3 = esrc[e + 3];
    float w0 = ew[e + 0], w1 = ew[e + 1], w2 = ew[e + 2], w3 = ew[e + 3];
    if constexpr (V == 4) {
      float4 h0 = *(const float4*)(H + (size_t)s0 * COLS + lane * 4);
      float4 h1 = *(const float4*)(H + (size_t)s1 * COLS + lane * 4);
      float4 h2 = *(const float4*)(H + (size_t)s2 * COLS + lane * 4);
      float4 h3 = *(const float4*)(H + (size_t)s3 * COLS + lane * 4);
      acc[0] = fmaf(w3, h3.x, fmaf(w2, h2.x, fmaf(w1, h1.x, fmaf(w0, h0.x, acc[0]))));
      acc[1] = fmaf(w3, h3.y, fmaf(w2, h2.y, fmaf(w1, h1.y, fmaf(w0, h0.y, acc[1]))));
      acc[2] = fmaf(w3, h3.z, fmaf(w2, h2.z, fmaf(w1, h1.z, fmaf(w0, h0.z, acc[2]))));
      acc[3] = fmaf(w3, h3.w, fmaf(w2, h2.w, fmaf(w1, h1.w, fmaf(w0, h0.w, acc[3]))));
    } else {
      float2 h0 = *(const float2*)(H + (size_t)s0 * COLS + lane * 2);
      float2 h1 = *(const float2*)(H + (size_t)s1 * COLS + lane * 2);
      float2 h2 = *(const float2*)(H + (size_t)s2 * COLS + lane * 2);
      float2 h3 = *(const float2*)(H + (size_t)s3 * COLS + lane * 2);
      acc[0] = fmaf(w3, h3.x, fmaf(w2, h2.x, fmaf(w1, h1.x, fmaf(w0, h0.x, acc[0]))));
      acc[1] = fmaf(w3, h3.y, fmaf(w2, h2.y, fmaf(w1, h1.y, fmaf(w0, h0.y, acc[1]))));
    }
  }
  for (; e < e1; ++e) {
    int s = esrc[e];
    float w = ew[e];
    if constexpr (V == 4) {
      float4 h = *(const float4*)(H + (size_t)s * COLS + lane * 4);
      acc[0] = fmaf(w, h.x, acc[0]);
      acc[1] = fmaf(w, h.y, acc[1]);
      acc[2] = fmaf(w, h.z, acc[2]);
      acc[3] = fmaf(w, h.w, acc[3]);
    } else {
      float2 h = *(const float2*)(H + (size_t)s * COLS + lane * 2);
      acc[0] = fmaf(w, h.x, acc[0]);
      acc[1] = fmaf(w, h.y, acc[1]);
    }
  }
  if constexpr (V == 4) {
    float4 b = *(const float4*)(bias + lane * 4);
    float4 o;
    o.x = fmaf(di, acc[0], b.x);
    o.y = fmaf(di, acc[1], b.y);
    o.z = fmaf(di, acc[2], b.z);
    o.w = fmaf(di, acc[3], b.w);
    *(float4*)(out + (size_t)node * COLS + lane * 4) = o;
  } else {
    float2 b = *(const float2*)(bias + lane * 2);
    float2 o;
    o.x = fmaf(di, acc[0], b.x);
    o.y = fmaf(di, acc[1], b.y);
    *(float2*)(out + (size_t)node * COLS + lane * 2) = o;
  }
}

// ---------------- launch ----------------

extern "C" void kernel_launch(void* const* d_in, const int* in_sizes, int n_in,
                              void* d_out, int out_size, void* d_ws, size_t ws_size,
                              hipStream_t stream) {
  (void)n_in; (void)out_size; (void)ws_size;
  const float* x = (const float*)d_in[0];
  const int N = in_sizes[0] / 256;
  const int* ei = (const int*)d_in[1];
  const int E = in_sizes[1] / 2;
  const int* srcp = ei;
  const int* dstp = ei + E;
  const float* Wl[6];
  const float* Bl[6];
  for (int i = 0; i < 6; i++) {
    Wl[i] = (const float*)d_in[2 + 2 * i];
    Bl[i] = (const float*)d_in[3 + 2 * i];
  }
  float* out = (float*)d_out;

  char* p = (char*)d_ws;
  auto carve = [&](size_t bytes) {
    char* r = p;
    p += (bytes + 255) & ~(size_t)255;
    return (void*)r;
  };
  float* bufA = (float*)carve((size_t)N * 256 * 4);
  float* bufB = (float*)carve((size_t)N * 256 * 4);
  int* cnt = (int*)carve((size_t)N * 4);
  float* dinv = (float*)carve((size_t)N * 4);
  int* incl = (int*)carve((size_t)N * 4);
  int* rowptr = (int*)carve((size_t)(N + 1) * 4);
  int* esrc = (int*)carve((size_t)E * 4);
  float* ew = (float*)carve((size_t)E * 4);
  int* bsum = (int*)carve(1024);
  int* boff = (int*)carve(1024);

  const int NB = (N + 255) / 256;

  hipMemsetAsync(cnt, 0, (size_t)N * 4, stream);
  hist_kernel<<<(E + 255) / 256, 256, 0, stream>>>(dstp, cnt, E);
  dinv_kernel<<<NB, 256, 0, stream>>>(cnt, dinv, N);
  scan1_kernel<<<NB, 256, 0, stream>>>(cnt, incl, bsum, N);
  scan2_kernel<<<1, 256, 0, stream>>>(bsum, boff, NB);
  scan3_kernel<<<NB, 256, 0, stream>>>(incl, boff, rowptr, N);
  hipMemsetAsync(cnt, 0, (size_t)N * 4, stream);
  scatter_kernel<<<(E + 255) / 256, 256, 0, stream>>>(srcp, dstp, rowptr, cnt, dinv,
                                                      esrc, ew, E);

  const int gm = (N + 127) / 128;
  const int gagg = (N + 3) / 4;

  // layer 1 (no lrelu on input)
  gemm_kernel<false, 256><<<dim3(gm, 2), 256, 0, stream>>>(x, Wl[0], bufB, N);
  aggregate_kernel<256><<<gagg, 256, 0, stream>>>(bufB, rowptr, esrc, ew, dinv, Bl[0], bufA, N);
  // layers 2..5
  for (int l = 1; l < 5; ++l) {
    gemm_kernel<true, 256><<<dim3(gm, 2), 256, 0, stream>>>(bufA, Wl[l], bufB, N);
    aggregate_kernel<256><<<gagg, 256, 0, stream>>>(bufB, rowptr, esrc, ew, dinv, Bl[l], bufA, N);
  }
  // layer 6 (out dim 128) -> d_out
  gemm_kernel<true, 128><<<dim3(gm, 1), 256, 0, stream>>>(bufA, Wl[5], bufB, N);
  aggregate_kernel<128><<<gagg, 256, 0, stream>>>(bufB, rowptr, esrc, ew, dinv, Bl[5], out, N);
}

// Round 7
// 1195.594 us; speedup vs baseline: 1.2938x; 1.2938x over previous
//
#include <hip/hip_runtime.h>

#define K_DIM 256
__device__ __forceinline__ float lrelu_f(float x) { return x >= 0.f ? x : 0.2f * x; }

// ---------------- graph prep kernels ----------------

__global__ __launch_bounds__(256) void hist_kernel(const int* __restrict__ dst,
                                                   int* __restrict__ cnt, int E) {
  int e = blockIdx.x * 256 + threadIdx.x;
  if (e < E) atomicAdd(&cnt[dst[e]], 1);
}

__global__ __launch_bounds__(256) void dinv_kernel(const int* __restrict__ cnt,
                                                   float* __restrict__ dinv, int n) {
  int i = blockIdx.x * 256 + threadIdx.x;
  if (i < n) dinv[i] = rsqrtf((float)cnt[i] + 1.0f);
}

__global__ __launch_bounds__(256) void scan1_kernel(const int* __restrict__ cnt,
                                                    int* __restrict__ incl,
                                                    int* __restrict__ bsum, int n) {
  __shared__ int sm[256];
  int t = threadIdx.x;
  int i = blockIdx.x * 256 + t;
  int v = (i < n) ? cnt[i] : 0;
  sm[t] = v;
  __syncthreads();
  for (int off = 1; off < 256; off <<= 1) {
    int u = (t >= off) ? sm[t - off] : 0;
    __syncthreads();
    sm[t] += u;
    __syncthreads();
  }
  if (i < n) incl[i] = sm[t];
  if (t == 255) bsum[blockIdx.x] = sm[255];
}

__global__ __launch_bounds__(256) void scan2_kernel(const int* __restrict__ bsum,
                                                    int* __restrict__ boff, int nb) {
  __shared__ int sm[256];
  int t = threadIdx.x;
  int v = (t < nb) ? bsum[t] : 0;
  sm[t] = v;
  __syncthreads();
  for (int off = 1; off < 256; off <<= 1) {
    int u = (t >= off) ? sm[t - off] : 0;
    __syncthreads();
    sm[t] += u;
    __syncthreads();
  }
  boff[t] = sm[t] - v;  // exclusive
}

__global__ __launch_bounds__(256) void scan3_kernel(const int* __restrict__ incl,
                                                    const int* __restrict__ boff,
                                                    int* __restrict__ rowptr, int n) {
  int i = blockIdx.x * 256 + threadIdx.x;
  if (i < n) rowptr[i + 1] = incl[i] + boff[blockIdx.x];
  if (i == 0) rowptr[0] = 0;
}

__global__ __launch_bounds__(256) void scatter_kernel(const int* __restrict__ src,
                                                      const int* __restrict__ dst,
                                                      const int* __restrict__ rowptr,
                                                      int* __restrict__ cursor,
                                                      const float* __restrict__ dinv,
                                                      int* __restrict__ esrc,
                                                      float* __restrict__ ew, int E) {
  int e = blockIdx.x * 256 + threadIdx.x;
  if (e < E) {
    int d = dst[e];
    int p = rowptr[d] + atomicAdd(&cursor[d], 1);
    int s = src[e];
    esrc[p] = s;
    ew[p] = dinv[s];
  }
}

// ---------------- GEMM (R4 single-buffer version: 80us, occ-healthy) ----------------
// 128x128 tile, 256 threads, 8x8 microtile (2x2 blocks of 4x4), BK=16.
// NOTE R6: double-buffer+prefetch variant hit VGPR=184 -> 9% occupancy -> 2x SLOWER.

template <bool LRELU, int NCOLS>
__global__ __launch_bounds__(256) void gemm_kernel(const float* __restrict__ A,
                                                   const float* __restrict__ W,
                                                   float* __restrict__ H, int M) {
  constexpr int BK = 16;
  __shared__ float As[BK][128];
  __shared__ float Ws[BK][128];
  const int bm = blockIdx.x * 128;
  const int bn = blockIdx.y * 128;
  const int tid = threadIdx.x;
  const int tx = tid & 15;   // N dir
  const int ty = tid >> 4;   // M dir
  const int lr = tid >> 2;   // staging row 0..63
  const int lk = (tid & 3) << 2;  // staging k quad

  float acc[2][2][4][4];
#pragma unroll
  for (int a = 0; a < 2; a++)
#pragma unroll
    for (int b = 0; b < 2; b++)
#pragma unroll
      for (int i = 0; i < 4; i++)
#pragma unroll
        for (int j = 0; j < 4; j++) acc[a][b][i][j] = 0.f;

  for (int k0 = 0; k0 < K_DIM; k0 += BK) {
#pragma unroll
    for (int h = 0; h < 2; ++h) {
      int row = bm + h * 64 + lr;
      int rc = row < M ? row : M - 1;
      float4 v = *(const float4*)(A + (size_t)rc * K_DIM + k0 + lk);
      if (LRELU) {
        v.x = lrelu_f(v.x); v.y = lrelu_f(v.y); v.z = lrelu_f(v.z); v.w = lrelu_f(v.w);
      }
      As[lk + 0][h * 64 + lr] = v.x;
      As[lk + 1][h * 64 + lr] = v.y;
      As[lk + 2][h * 64 + lr] = v.z;
      As[lk + 3][h * 64 + lr] = v.w;
    }
#pragma unroll
    for (int h = 0; h < 2; ++h) {
      int row = bn + h * 64 + lr;
      float4 v = *(const float4*)(W + (size_t)row * K_DIM + k0 + lk);
      Ws[lk + 0][h * 64 + lr] = v.x;
      Ws[lk + 1][h * 64 + lr] = v.y;
      Ws[lk + 2][h * 64 + lr] = v.z;
      Ws[lk + 3][h * 64 + lr] = v.w;
    }
    __syncthreads();
#pragma unroll
    for (int kk = 0; kk < BK; ++kk) {
      float4 va0 = *(const float4*)&As[kk][ty * 4];
      float4 va1 = *(const float4*)&As[kk][64 + ty * 4];
      float4 vb0 = *(const float4*)&Ws[kk][tx * 4];
      float4 vb1 = *(const float4*)&Ws[kk][64 + tx * 4];
      float a0[4] = {va0.x, va0.y, va0.z, va0.w};
      float a1[4] = {va1.x, va1.y, va1.z, va1.w};
      float b0[4] = {vb0.x, vb0.y, vb0.z, vb0.w};
      float b1[4] = {vb1.x, vb1.y, vb1.z, vb1.w};
#pragma unroll
      for (int i = 0; i < 4; i++)
#pragma unroll
        for (int j = 0; j < 4; j++) {
          acc[0][0][i][j] = fmaf(a0[i], b0[j], acc[0][0][i][j]);
          acc[0][1][i][j] = fmaf(a0[i], b1[j], acc[0][1][i][j]);
          acc[1][0][i][j] = fmaf(a1[i], b0[j], acc[1][0][i][j]);
          acc[1][1][i][j] = fmaf(a1[i], b1[j], acc[1][1][i][j]);
        }
    }
    __syncthreads();
  }

#pragma unroll
  for (int mh = 0; mh < 2; ++mh)
#pragma unroll
    for (int i = 0; i < 4; i++) {
      int row = bm + mh * 64 + ty * 4 + i;
      if (row < M) {
#pragma unroll
        for (int nh = 0; nh < 2; ++nh) {
          float4 o;
          o.x = acc[mh][nh][i][0];
          o.y = acc[mh][nh][i][1];
          o.z = acc[mh][nh][i][2];
          o.w = acc[mh][nh][i][3];
          *(float4*)(H + (size_t)row * NCOLS + bn + nh * 64 + tx * 4) = o;
        }
      }
    }
}

// ---------------- column-sliced aggregation ----------------
// out[i] = dinv_i*(sum_e dinv_s*h_s) + dinv_i^2*h_i + b
// Col-group g = blockIdx.x & 7 rides the round-robin workgroup->XCD dispatch:
// all blocks touching cols [g*CW, (g+1)*CW) land on XCD g, so each XCD's L2
// only ever sees a 1/8 column slice of H (6.4 MB unique vs 51 MB whole-H).
// Device-wide fetch floor drops ~8x vs whole-row gathers (R2-R4: 401 MB/layer).
// TPN threads (float4 each) per node; 4-way edge batching for MLP.

template <int COLS>
__global__ __launch_bounds__(256) void aggregate_kernel(
    const float* __restrict__ H, const int* __restrict__ rowptr,
    const int* __restrict__ esrc, const float* __restrict__ ew,
    const float* __restrict__ dinv, const float* __restrict__ bias,
    float* __restrict__ out, int n) {
  constexpr int CW = COLS / 8;    // cols per group: 32 (COLS=256) or 16 (COLS=128)
  constexpr int TPN = CW / 4;     // threads per node: 8 or 4
  constexpr int NPB = 256 / TPN;  // nodes per block: 32 or 64
  const int g = blockIdx.x & 7;
  const int nb = blockIdx.x >> 3;
  const int t = threadIdx.x;
  const int ln = t / TPN;
  const int ct = t % TPN;
  const int node = nb * NPB + ln;
  if (node >= n) return;
  const int c0 = g * CW + ct * 4;
  const float* __restrict__ Hc = H + c0;
  const float di = dinv[node];

  float4 hs = *(const float4*)(Hc + (size_t)node * COLS);
  float a0 = di * hs.x, a1 = di * hs.y, a2 = di * hs.z, a3 = di * hs.w;

  const int e1 = rowptr[node + 1];
  int e = rowptr[node];
  for (; e + 4 <= e1; e += 4) {
    int s0 = esrc[e + 0], s1 = esrc[e + 1], s2 = esrc[e + 2], s3 = esrc[e + 3];
    float w0 = ew[e + 0], w1 = ew[e + 1], w2 = ew[e + 2], w3 = ew[e + 3];
    float4 h0 = *(const float4*)(Hc + (size_t)s0 * COLS);
    float4 h1 = *(const float4*)(Hc + (size_t)s1 * COLS);
    float4 h2 = *(const float4*)(Hc + (size_t)s2 * COLS);
    float4 h3 = *(const float4*)(Hc + (size_t)s3 * COLS);
    a0 = fmaf(w3, h3.x, fmaf(w2, h2.x, fmaf(w1, h1.x, fmaf(w0, h0.x, a0))));
    a1 = fmaf(w3, h3.y, fmaf(w2, h2.y, fmaf(w1, h1.y, fmaf(w0, h0.y, a1))));
    a2 = fmaf(w3, h3.z, fmaf(w2, h2.z, fmaf(w1, h1.z, fmaf(w0, h0.z, a2))));
    a3 = fmaf(w3, h3.w, fmaf(w2, h2.w, fmaf(w1, h1.w, fmaf(w0, h0.w, a3))));
  }
  for (; e < e1; ++e) {
    int s = esrc[e];
    float w = ew[e];
    float4 h = *(const float4*)(Hc + (size_t)s * COLS);
    a0 = fmaf(w, h.x, a0);
    a1 = fmaf(w, h.y, a1);
    a2 = fmaf(w, h.z, a2);
    a3 = fmaf(w, h.w, a3);
  }

  float4 b = *(const float4*)(bias + c0);
  float4 o;
  o.x = fmaf(di, a0, b.x);
  o.y = fmaf(di, a1, b.y);
  o.z = fmaf(di, a2, b.z);
  o.w = fmaf(di, a3, b.w);
  *(float4*)(out + (size_t)node * COLS + c0) = o;
}

// ---------------- launch ----------------

extern "C" void kernel_launch(void* const* d_in, const int* in_sizes, int n_in,
                              void* d_out, int out_size, void* d_ws, size_t ws_size,
                              hipStream_t stream) {
  (void)n_in; (void)out_size; (void)ws_size;
  const float* x = (const float*)d_in[0];
  const int N = in_sizes[0] / 256;
  const int* ei = (const int*)d_in[1];
  const int E = in_sizes[1] / 2;
  const int* srcp = ei;
  const int* dstp = ei + E;
  const float* Wl[6];
  const float* Bl[6];
  for (int i = 0; i < 6; i++) {
    Wl[i] = (const float*)d_in[2 + 2 * i];
    Bl[i] = (const float*)d_in[3 + 2 * i];
  }
  float* out = (float*)d_out;

  char* p = (char*)d_ws;
  auto carve = [&](size_t bytes) {
    char* r = p;
    p += (bytes + 255) & ~(size_t)255;
    return (void*)r;
  };
  float* bufA = (float*)carve((size_t)N * 256 * 4);
  float* bufB = (float*)carve((size_t)N * 256 * 4);
  int* cnt = (int*)carve((size_t)N * 4);
  float* dinv = (float*)carve((size_t)N * 4);
  int* incl = (int*)carve((size_t)N * 4);
  int* rowptr = (int*)carve((size_t)(N + 1) * 4);
  int* esrc = (int*)carve((size_t)E * 4);
  float* ew = (float*)carve((size_t)E * 4);
  int* bsum = (int*)carve(1024);
  int* boff = (int*)carve(1024);

  const int NB = (N + 255) / 256;

  hipMemsetAsync(cnt, 0, (size_t)N * 4, stream);
  hist_kernel<<<(E + 255) / 256, 256, 0, stream>>>(dstp, cnt, E);
  dinv_kernel<<<NB, 256, 0, stream>>>(cnt, dinv, N);
  scan1_kernel<<<NB, 256, 0, stream>>>(cnt, incl, bsum, N);
  scan2_kernel<<<1, 256, 0, stream>>>(bsum, boff, NB);
  scan3_kernel<<<NB, 256, 0, stream>>>(incl, boff, rowptr, N);
  hipMemsetAsync(cnt, 0, (size_t)N * 4, stream);
  scatter_kernel<<<(E + 255) / 256, 256, 0, stream>>>(srcp, dstp, rowptr, cnt, dinv,
                                                      esrc, ew, E);

  const int gm = (N + 127) / 128;
  const int gagg256 = 8 * ((N + 31) / 32);   // 8 col groups x node blocks
  const int gagg128 = 8 * ((N + 63) / 64);

  // layer 1 (no lrelu on input)
  gemm_kernel<false, 256><<<dim3(gm, 2), 256, 0, stream>>>(x, Wl[0], bufB, N);
  aggregate_kernel<256><<<gagg256, 256, 0, stream>>>(bufB, rowptr, esrc, ew, dinv, Bl[0], bufA, N);
  // layers 2..5
  for (int l = 1; l < 5; ++l) {
    gemm_kernel<true, 256><<<dim3(gm, 2), 256, 0, stream>>>(bufA, Wl[l], bufB, N);
    aggregate_kernel<256><<<gagg256, 256, 0, stream>>>(bufB, rowptr, esrc, ew, dinv, Bl[l], bufA, N);
  }
  // layer 6 (out dim 128) -> d_out
  gemm_kernel<true, 128><<<dim3(gm, 1), 256, 0, stream>>>(bufA, Wl[5], bufB, N);
  aggregate_kernel<128><<<gagg128, 256, 0, stream>>>(bufB, rowptr, esrc, ew, dinv, Bl[5], out, N);
}

// Round 8
// 1188.478 us; speedup vs baseline: 1.3016x; 1.0060x over previous
//
#include <hip/hip_runtime.h>

#define K_DIM 256
__device__ __forceinline__ float lrelu_f(float x) { return x >= 0.f ? x : 0.2f * x; }

// ---------------- graph prep kernels ----------------

__global__ __launch_bounds__(256) void hist_kernel(const int* __restrict__ dst,
                                                   int* __restrict__ cnt, int E) {
  int e = blockIdx.x * 256 + threadIdx.x;
  if (e < E) atomicAdd(&cnt[dst[e]], 1);
}

__global__ __launch_bounds__(256) void dinv_kernel(const int* __restrict__ cnt,
                                                   float* __restrict__ dinv, int n) {
  int i = blockIdx.x * 256 + threadIdx.x;
  if (i < n) dinv[i] = rsqrtf((float)cnt[i] + 1.0f);
}

__global__ __launch_bounds__(256) void scan1_kernel(const int* __restrict__ cnt,
                                                    int* __restrict__ incl,
                                                    int* __restrict__ bsum, int n) {
  __shared__ int sm[256];
  int t = threadIdx.x;
  int i = blockIdx.x * 256 + t;
  int v = (i < n) ? cnt[i] : 0;
  sm[t] = v;
  __syncthreads();
  for (int off = 1; off < 256; off <<= 1) {
    int u = (t >= off) ? sm[t - off] : 0;
    __syncthreads();
    sm[t] += u;
    __syncthreads();
  }
  if (i < n) incl[i] = sm[t];
  if (t == 255) bsum[blockIdx.x] = sm[255];
}

__global__ __launch_bounds__(256) void scan2_kernel(const int* __restrict__ bsum,
                                                    int* __restrict__ boff, int nb) {
  __shared__ int sm[256];
  int t = threadIdx.x;
  int v = (t < nb) ? bsum[t] : 0;
  sm[t] = v;
  __syncthreads();
  for (int off = 1; off < 256; off <<= 1) {
    int u = (t >= off) ? sm[t - off] : 0;
    __syncthreads();
    sm[t] += u;
    __syncthreads();
  }
  boff[t] = sm[t] - v;  // exclusive
}

__global__ __launch_bounds__(256) void scan3_kernel(const int* __restrict__ incl,
                                                    const int* __restrict__ boff,
                                                    int* __restrict__ rowptr, int n) {
  int i = blockIdx.x * 256 + threadIdx.x;
  if (i < n) rowptr[i + 1] = incl[i] + boff[blockIdx.x];
  if (i == 0) rowptr[0] = 0;
}

__global__ __launch_bounds__(256) void scatter_kernel(const int* __restrict__ src,
                                                      const int* __restrict__ dst,
                                                      const int* __restrict__ rowptr,
                                                      int* __restrict__ cursor,
                                                      const float* __restrict__ dinv,
                                                      int* __restrict__ esrc,
                                                      float* __restrict__ ew, int E) {
  int e = blockIdx.x * 256 + threadIdx.x;
  if (e < E) {
    int d = dst[e];
    int p = rowptr[d] + atomicAdd(&cursor[d], 1);
    int s = src[e];
    esrc[p] = s;
    ew[p] = dinv[s];
  }
}

// ---------------- GEMM: H[M,NCOLS] = act(A[M,256]) @ W[NCOLS,256]^T ----------------
// 128x128 tile, 256 threads, 8x8 microtile (2x2 blocks of 4x4).
// R8 changes vs R4: (a) LDS row stride 128->132 so staging-write bank =
// (4k+c)%32 -> 2-way (was 4-way, 4.8M conflicts measured); (b) BK 16->32:
// halves barrier count (8 K-steps), doubles FMA run per barrier. LDS 33.8KB.
// NOTE R6: dbuf+prefetch variant hit VGPR=184 -> 9% occ -> 2x SLOWER. Keep single-buffer.

template <bool LRELU, int NCOLS>
__global__ __launch_bounds__(256) void gemm_kernel(const float* __restrict__ A,
                                                   const float* __restrict__ W,
                                                   float* __restrict__ H, int M) {
  constexpr int BK = 32;
  constexpr int PAD = 132;
  __shared__ float As[BK][PAD];
  __shared__ float Ws[BK][PAD];
  const int bm = blockIdx.x * 128;
  const int bn = blockIdx.y * 128;
  const int tid = threadIdx.x;
  const int tx = tid & 15;   // N dir
  const int ty = tid >> 4;   // M dir
  const int lr = tid >> 2;   // staging row 0..63
  const int lk = (tid & 3) << 2;  // staging k quad

  float acc[2][2][4][4];
#pragma unroll
  for (int a = 0; a < 2; a++)
#pragma unroll
    for (int b = 0; b < 2; b++)
#pragma unroll
      for (int i = 0; i < 4; i++)
#pragma unroll
        for (int j = 0; j < 4; j++) acc[a][b][i][j] = 0.f;

  for (int k0 = 0; k0 < K_DIM; k0 += BK) {
#pragma unroll
    for (int kh = 0; kh < 2; ++kh) {
      const int ks = kh * 16 + lk;
#pragma unroll
      for (int h = 0; h < 2; ++h) {
        int row = bm + h * 64 + lr;
        int rc = row < M ? row : M - 1;
        float4 v = *(const float4*)(A + (size_t)rc * K_DIM + k0 + ks);
        if (LRELU) {
          v.x = lrelu_f(v.x); v.y = lrelu_f(v.y); v.z = lrelu_f(v.z); v.w = lrelu_f(v.w);
        }
        As[ks + 0][h * 64 + lr] = v.x;
        As[ks + 1][h * 64 + lr] = v.y;
        As[ks + 2][h * 64 + lr] = v.z;
        As[ks + 3][h * 64 + lr] = v.w;
      }
#pragma unroll
      for (int h = 0; h < 2; ++h) {
        int row = bn + h * 64 + lr;
        float4 v = *(const float4*)(W + (size_t)row * K_DIM + k0 + ks);
        Ws[ks + 0][h * 64 + lr] = v.x;
        Ws[ks + 1][h * 64 + lr] = v.y;
        Ws[ks + 2][h * 64 + lr] = v.z;
        Ws[ks + 3][h * 64 + lr] = v.w;
      }
    }
    __syncthreads();
#pragma unroll 8
    for (int kk = 0; kk < BK; ++kk) {
      float4 va0 = *(const float4*)&As[kk][ty * 4];
      float4 va1 = *(const float4*)&As[kk][64 + ty * 4];
      float4 vb0 = *(const float4*)&Ws[kk][tx * 4];
      float4 vb1 = *(const float4*)&Ws[kk][64 + tx * 4];
      float a0[4] = {va0.x, va0.y, va0.z, va0.w};
      float a1[4] = {va1.x, va1.y, va1.z, va1.w};
      float b0[4] = {vb0.x, vb0.y, vb0.z, vb0.w};
      float b1[4] = {vb1.x, vb1.y, vb1.z, vb1.w};
#pragma unroll
      for (int i = 0; i < 4; i++)
#pragma unroll
        for (int j = 0; j < 4; j++) {
          acc[0][0][i][j] = fmaf(a0[i], b0[j], acc[0][0][i][j]);
          acc[0][1][i][j] = fmaf(a0[i], b1[j], acc[0][1][i][j]);
          acc[1][0][i][j] = fmaf(a1[i], b0[j], acc[1][0][i][j]);
          acc[1][1][i][j] = fmaf(a1[i], b1[j], acc[1][1][i][j]);
        }
    }
    __syncthreads();
  }

#pragma unroll
  for (int mh = 0; mh < 2; ++mh)
#pragma unroll
    for (int i = 0; i < 4; i++) {
      int row = bm + mh * 64 + ty * 4 + i;
      if (row < M) {
#pragma unroll
        for (int nh = 0; nh < 2; ++nh) {
          float4 o;
          o.x = acc[mh][nh][i][0];
          o.y = acc[mh][nh][i][1];
          o.z = acc[mh][nh][i][2];
          o.w = acc[mh][nh][i][3];
          *(float4*)(H + (size_t)row * NCOLS + bn + nh * 64 + tx * 4) = o;
        }
      }
    }
}

// ---------------- column-sliced aggregation (R7: WORKS, 124->~88us) ----------------
// out[i] = dinv_i*(sum_e dinv_s*h_s) + dinv_i^2*h_i + b
// Col-group g = blockIdx.x & 7 rides round-robin workgroup->XCD dispatch:
// each XCD's L2 sees a 1/8 column slice of H (6.4 MB unique vs 51 MB).

template <int COLS>
__global__ __launch_bounds__(256) void aggregate_kernel(
    const float* __restrict__ H, const int* __restrict__ rowptr,
    const int* __restrict__ esrc, const float* __restrict__ ew,
    const float* __restrict__ dinv, const float* __restrict__ bias,
    float* __restrict__ out, int n) {
  constexpr int CW = COLS / 8;    // cols per group: 32 (COLS=256) or 16 (COLS=128)
  constexpr int TPN = CW / 4;     // threads per node: 8 or 4
  constexpr int NPB = 256 / TPN;  // nodes per block: 32 or 64
  const int g = blockIdx.x & 7;
  const int nb = blockIdx.x >> 3;
  const int t = threadIdx.x;
  const int ln = t / TPN;
  const int ct = t % TPN;
  const int node = nb * NPB + ln;
  if (node >= n) return;
  const int c0 = g * CW + ct * 4;
  const float* __restrict__ Hc = H + c0;
  const float di = dinv[node];

  float4 hs = *(const float4*)(Hc + (size_t)node * COLS);
  float a0 = di * hs.x, a1 = di * hs.y, a2 = di * hs.z, a3 = di * hs.w;

  const int e1 = rowptr[node + 1];
  int e = rowptr[node];
  for (; e + 4 <= e1; e += 4) {
    int s0 = esrc[e + 0], s1 = esrc[e + 1], s2 = esrc[e + 2], s3 = esrc[e + 3];
    float w0 = ew[e + 0], w1 = ew[e + 1], w2 = ew[e + 2], w3 = ew[e + 3];
    float4 h0 = *(const float4*)(Hc + (size_t)s0 * COLS);
    float4 h1 = *(const float4*)(Hc + (size_t)s1 * COLS);
    float4 h2 = *(const float4*)(Hc + (size_t)s2 * COLS);
    float4 h3 = *(const float4*)(Hc + (size_t)s3 * COLS);
    a0 = fmaf(w3, h3.x, fmaf(w2, h2.x, fmaf(w1, h1.x, fmaf(w0, h0.x, a0))));
    a1 = fmaf(w3, h3.y, fmaf(w2, h2.y, fmaf(w1, h1.y, fmaf(w0, h0.y, a1))));
    a2 = fmaf(w3, h3.z, fmaf(w2, h2.z, fmaf(w1, h1.z, fmaf(w0, h0.z, a2))));
    a3 = fmaf(w3, h3.w, fmaf(w2, h2.w, fmaf(w1, h1.w, fmaf(w0, h0.w, a3))));
  }
  for (; e < e1; ++e) {
    int s = esrc[e];
    float w = ew[e];
    float4 h = *(const float4*)(Hc + (size_t)s * COLS);
    a0 = fmaf(w, h.x, a0);
    a1 = fmaf(w, h.y, a1);
    a2 = fmaf(w, h.z, a2);
    a3 = fmaf(w, h.w, a3);
  }

  float4 b = *(const float4*)(bias + c0);
  float4 o;
  o.x = fmaf(di, a0, b.x);
  o.y = fmaf(di, a1, b.y);
  o.z = fmaf(di, a2, b.z);
  o.w = fmaf(di, a3, b.w);
  *(float4*)(out + (size_t)node * COLS + c0) = o;
}

// ---------------- launch ----------------

extern "C" void kernel_launch(void* const* d_in, const int* in_sizes, int n_in,
                              void* d_out, int out_size, void* d_ws, size_t ws_size,
                              hipStream_t stream) {
  (void)n_in; (void)out_size; (void)ws_size;
  const float* x = (const float*)d_in[0];
  const int N = in_sizes[0] / 256;
  const int* ei = (const int*)d_in[1];
  const int E = in_sizes[1] / 2;
  const int* srcp = ei;
  const int* dstp = ei + E;
  const float* Wl[6];
  const float* Bl[6];
  for (int i = 0; i < 6; i++) {
    Wl[i] = (const float*)d_in[2 + 2 * i];
    Bl[i] = (const float*)d_in[3 + 2 * i];
  }
  float* out = (float*)d_out;

  char* p = (char*)d_ws;
  auto carve = [&](size_t bytes) {
    char* r = p;
    p += (bytes + 255) & ~(size_t)255;
    return (void*)r;
  };
  float* bufA = (float*)carve((size_t)N * 256 * 4);
  float* bufB = (float*)carve((size_t)N * 256 * 4);
  int* cnt = (int*)carve((size_t)N * 4);
  float* dinv = (float*)carve((size_t)N * 4);
  int* incl = (int*)carve((size_t)N * 4);
  int* rowptr = (int*)carve((size_t)(N + 1) * 4);
  int* esrc = (int*)carve((size_t)E * 4);
  float* ew = (float*)carve((size_t)E * 4);
  int* bsum = (int*)carve(1024);
  int* boff = (int*)carve(1024);

  const int NB = (N + 255) / 256;

  hipMemsetAsync(cnt, 0, (size_t)N * 4, stream);
  hist_kernel<<<(E + 255) / 256, 256, 0, stream>>>(dstp, cnt, E);
  dinv_kernel<<<NB, 256, 0, stream>>>(cnt, dinv, N);
  scan1_kernel<<<NB, 256, 0, stream>>>(cnt, incl, bsum, N);
  scan2_kernel<<<1, 256, 0, stream>>>(bsum, boff, NB);
  scan3_kernel<<<NB, 256, 0, stream>>>(incl, boff, rowptr, N);
  hipMemsetAsync(cnt, 0, (size_t)N * 4, stream);
  scatter_kernel<<<(E + 255) / 256, 256, 0, stream>>>(srcp, dstp, rowptr, cnt, dinv,
                                                      esrc, ew, E);

  const int gm = (N + 127) / 128;
  const int gagg256 = 8 * ((N + 31) / 32);   // 8 col groups x node blocks
  const int gagg128 = 8 * ((N + 63) / 64);

  // layer 1 (no lrelu on input)
  gemm_kernel<false, 256><<<dim3(gm, 2), 256, 0, stream>>>(x, Wl[0], bufB, N);
  aggregate_kernel<256><<<gagg256, 256, 0, stream>>>(bufB, rowptr, esrc, ew, dinv, Bl[0], bufA, N);
  // layers 2..5
  for (int l = 1; l < 5; ++l) {
    gemm_kernel<true, 256><<<dim3(gm, 2), 256, 0, stream>>>(bufA, Wl[l], bufB, N);
    aggregate_kernel<256><<<gagg256, 256, 0, stream>>>(bufB, rowptr, esrc, ew, dinv, Bl[l], bufA, N);
  }
  // layer 6 (out dim 128) -> d_out
  gemm_kernel<true, 128><<<dim3(gm, 1), 256, 0, stream>>>(bufA, Wl[5], bufB, N);
  aggregate_kernel<128><<<gagg128, 256, 0, stream>>>(bufB, rowptr, esrc, ew, dinv, Bl[5], out, N);
}